// Round 14
// baseline (128.120 us; speedup 1.0000x reference)
//
#include <hip/hip_runtime.h>
#include <stdint.h>

typedef __attribute__((ext_vector_type(4))) float f32x4;
typedef __attribute__((ext_vector_type(2))) unsigned int u32x2;
typedef __attribute__((ext_vector_type(4))) unsigned int u32x4;

#define NROW 4096
#define DDIM 512
#define NT   22            // tiles per dim
#define TS   192
#define NPAD 4224

// ---------------- ws layout (bytes) ----------------
#define WB_OFF   0u          // fp8[4224*512] = 2162688
#define GB_OFF   2162688u    // fp8[4224*512]
#define SQBW_OFF 4325376u    // float[4224]
#define SQBG_OFF 4342272u    // float[4224]
#define SCS_OFF  4359168u    // float[32][512] (zeroed)
#define SSP_OFF  4424704u    // double[256]    (zeroed)
#define PU_OFF   4426752u    // float[22][22][192] = 371712 (fully written)
#define PV_OFF   4798464u    // float[22][22][192]
#define PSL_OFF  5170176u    // double[484]    (fully written)
#define ZERO_BEG SCS_OFF
#define ZERO_END (SSP_OFF + 2048u)

// raw barrier: drains LDS ops only — in-flight global loads stay in flight (T4)
#define BAR_LGKM() asm volatile("s_waitcnt lgkmcnt(0)\n\ts_barrier" ::: "memory")

__device__ __forceinline__ void atomAddF64(double* p, double v) {
  __hip_atomic_fetch_add(p, v, __ATOMIC_RELAXED, __HIP_MEMORY_SCOPE_AGENT);
}
__device__ __forceinline__ void atomAddF32(float* p, float v) {
  __hip_atomic_fetch_add(p, v, __ATOMIC_RELAXED, __HIP_MEMORY_SCOPE_AGENT);
}

// fast 2^x (x <= 0, modest |x|; denormal flush harmless) — validated R11
__device__ __forceinline__ float fexp2(float x) {
  float r;
  asm("v_exp_f32 %0, %1" : "=v"(r) : "v"(x));
  return r;
}

// ---- fp8 e4m3fn helpers ----
__device__ __forceinline__ float fp8dec(unsigned b) {
  unsigned e = (b >> 3) & 15u, m = b & 7u;
  float v = ldexpf((float)(e ? (m | 8u) : m), (int)e - 10 + (e == 0));
  return (b & 0x80u) ? -v : v;
}

__device__ __forceinline__ unsigned f2fp8_manual(float f) {
  unsigned u = __float_as_uint(f);
  unsigned s = (u >> 24) & 0x80u;
  float a = __uint_as_float(u & 0x7FFFFFFFu);
  if (a >= 448.f) return s | 0x7Eu;
  if (a >= 0.015625f) {
    unsigned au = __float_as_uint(a);
    au += 0x7FFFFu + ((au >> 20) & 1u);
    unsigned e = (au >> 23) - 120u;
    unsigned m = (au >> 20) & 7u;
    if (e >= 16u) return s | 0x7Eu;
    return s | (e << 3) | m;
  }
  int q = (int)rintf(a * 512.f);
  return s | (unsigned)q;
}

#if __has_builtin(__builtin_amdgcn_cvt_pk_fp8_f32)
__device__ __forceinline__ unsigned pack4_fp8(float x0, float x1, float x2, float x3) {
  unsigned p = __builtin_amdgcn_cvt_pk_fp8_f32(x0, x1, 0, false);
  p = __builtin_amdgcn_cvt_pk_fp8_f32(x2, x3, p, true);
  return p;
}
#else
__device__ __forceinline__ unsigned pack4_fp8(float x0, float x1, float x2, float x3) {
  return f2fp8_manual(x0) | (f2fp8_manual(x1) << 8) |
         (f2fp8_manual(x2) << 16) | (f2fp8_manual(x3) << 24);
}
#endif

// ---- prep (R8 verbatim): fp32->fp8, fp8-consistent row sumsq, fused column sums
__global__ __launch_bounds__(256) void prep_rows(
    const float* __restrict__ W, const float* __restrict__ G,
    unsigned char* __restrict__ Wb, unsigned char* __restrict__ Gb,
    float* __restrict__ sqbW, float* __restrict__ sqbG,
    double* __restrict__ ssp, float* __restrict__ scs)
{
  __shared__ float cols[4][512];
  const int bid = blockIdx.x;
  const int w = threadIdx.x >> 6;
  const int l = threadIdx.x & 63;

  if (bid >= 2048) {                       // pad-row zeroing blocks
    const int pr = (bid - 2048) * 4 + w;   // 0..255
    const bool isG = pr >= 128;
    const int row = NROW + (pr & 127);     // 4096..4223
    unsigned char* dst = (isG ? Gb : Wb) + (size_t)row * DDIM;
    *(u32x2*)(dst + l * 8) = (u32x2){0u, 0u};
    if (l == 0) (isG ? sqbG : sqbW)[row] = 0.f;
    return;
  }

  const int row = bid * 4 + w;             // 0..8191
  const float* src; unsigned char* dst; float* sqb; int r;
  if (row < NROW) { src = W + (size_t)row * DDIM; dst = Wb + (size_t)row * DDIM; sqb = sqbW; r = row; }
  else            { src = G + (size_t)(row - NROW) * DDIM; dst = Gb + (size_t)(row - NROW) * DDIM; sqb = sqbG; r = row - NROW; }
  const f32x4 a = *(const f32x4*)(src + l * 8);
  const f32x4 b = *(const f32x4*)(src + l * 8 + 4);

  const unsigned p0 = pack4_fp8(a[0], a[1], a[2], a[3]);
  const unsigned p1 = pack4_fp8(b[0], b[1], b[2], b[3]);
  *(u32x2*)(dst + l * 8) = (u32x2){p0, p1};

  float s32 = 0.f, sb = 0.f;
  #pragma unroll
  for (int j = 0; j < 4; ++j) { s32 += a[j] * a[j]; s32 += b[j] * b[j]; }
  #pragma unroll
  for (int j = 0; j < 4; ++j) {
    float xa = fp8dec((p0 >> (8 * j)) & 0xFFu);
    float xb = fp8dec((p1 >> (8 * j)) & 0xFFu);
    sb += xa * xa + xb * xb;
  }

  *(f32x4*)&cols[w][l * 8] = a;
  *(f32x4*)&cols[w][l * 8 + 4] = b;
  __syncthreads();
  for (int c = threadIdx.x; c < 512; c += 256)
    atomAddF32(&scs[(bid & 31) * 512 + c],
               cols[0][c] + cols[1][c] + cols[2][c] + cols[3][c]);

  #pragma unroll
  for (int off = 32; off > 0; off >>= 1) { s32 += __shfl_down(s32, off); sb += __shfl_down(sb, off); }
  if (l == 0) { sqb[r] = sb; atomAddF64(&ssp[bid & 255], (double)s32); }
}

// ---- issue 6 global_load_dwordx4 for one BK=64 step into regs (T14 issue-early).
__device__ __forceinline__ void issue_loads(
    const unsigned char* __restrict__ Wb, const unsigned char* __restrict__ Gb,
    int i0, int j0, int st, int tid, u32x4 r[6])
{
  const int kb = st * 64;
  #pragma unroll
  for (int q = 0; q < 6; ++q) {
    const int slot = q * 512 + tid;   // 0..3071, 16B each; panels of 768 slots
    int p;
    if (q == 0) p = 0;
    else if (q == 1) p = (slot < 768) ? 0 : 1;
    else if (q == 2) p = 1;
    else if (q == 3) p = 2;
    else if (q == 4) p = (slot < 2304) ? 2 : 3;
    else p = 3;
    const unsigned char* mat = (p < 2) ? Wb : Gb;
    const int rb = (p & 1) ? j0 : i0;
    const int rr = slot - p * 768;
    const int row = rr >> 2;
    const int c = (rr & 3) ^ ((row >> 1) & 3);
    r[q] = *(const u32x4*)(mat + (size_t)(rb + row) * 512 + kb + c * 16);
  }
}

// ---- write staged regs to LDS (linear slots; ds_write_b128)
__device__ __forceinline__ void write_lds(int tid, const u32x4 r[6],
                                          unsigned char* __restrict__ buf)
{
  #pragma unroll
  for (int q = 0; q < 6; ++q) {
    const int slot = q * 512 + tid;
    *(u32x4*)(buf + slot * 16) = r[q];
  }
}

// ---- one K=64 step (2 x K=32 MFMA) for one gram (R6 verbatim)
__device__ __forceinline__ void gram_pass(
    const unsigned char* __restrict__ A, const unsigned char* __restrict__ B,
    int wr, int wc, int lr, int g, f32x4 acc[6][3])
{
  #pragma unroll
  for (int kk = 0; kk < 2; ++kk) {
    long long a[6], b[3];
    #pragma unroll
    for (int m = 0; m < 6; ++m) {
      const int row = wr * 96 + m * 16 + lr;
      const int off = row * 64 + (((kk * 2 + (g >> 1)) ^ ((row >> 1) & 3)) << 4) + ((g & 1) << 3);
      a[m] = *(const long long*)(A + off);
    }
    #pragma unroll
    for (int n = 0; n < 3; ++n) {
      const int row = wc * 48 + n * 16 + lr;
      const int off = row * 64 + (((kk * 2 + (g >> 1)) ^ ((row >> 1) & 3)) << 4) + ((g & 1) << 3);
      b[n] = *(const long long*)(B + off);
    }
    __builtin_amdgcn_s_setprio(1);
    #pragma unroll
    for (int m = 0; m < 6; ++m)
      #pragma unroll
      for (int n = 0; n < 3; ++n)
        acc[m][n] = __builtin_amdgcn_mfma_f32_16x16x32_fp8_fp8(a[m], b[n], acc[m][n], 0, 0, 0);
    __builtin_amdgcn_s_setprio(0);
  }
}

// ---- main: FULL 22x22 grid, persistent 256 blocks, XCD-banded tile lists so each
// XCD's panel working set (~3.3 MB) fits its private 4 MiB L2 (anti-thrash).
__global__ __launch_bounds__(512, 1) void gram_kernel(
    const unsigned char* __restrict__ Wb, const unsigned char* __restrict__ Gb,
    const float* __restrict__ sqbW, const float* __restrict__ sqbG,
    const float* __restrict__ scs, const double* __restrict__ ssp,
    float* __restrict__ PU, float* __restrict__ PV, double* __restrict__ PSL)
{
  __shared__ __align__(16) unsigned char lds[2][49152];  // dbuf: AW|BW|AG|BG each
  __shared__ float L[384];   // rowW|rowG reduction arrays
  __shared__ double pred[8], pred2[8];
  __shared__ float sS4;

  // persistent mapping: XCD x = blockIdx&7 (HW round-robin), slot s = blockIdx>>3.
  // XCD (rb=x>>2, cb=x&3): rows [rb*11, rb*11+11), cols band cb of sizes {6,6,5,5}.
  const int x = blockIdx.x & 7;
  const int s = blockIdx.x >> 3;
  const int rb = x >> 2;
  const int cb = x & 3;
  const int rstart = rb * 11;
  const int cstart = cb * 6 - (cb == 3 ? 1 : 0);   // 0,6,12,17
  const int csz = (cb < 2) ? 6 : 5;
  const int T = 11 * csz;

  const int tid = threadIdx.x;
  const int lane = tid & 63;
  const int wid = tid >> 6;
  const int wr = wid >> 2;      // 0..1  (96-row half)
  const int wc = wid & 3;       // 0..3  (48-col quarter)
  const int g = lane >> 4;
  const int lr = lane & 15;

  // first tile coords + prologue loads (flight hides under bwk below)
  int t0 = s;
  int bi = rstart + (t0 % 11);
  int bj = cstart + (t0 / 11);
  u32x4 rA[6], rB[6];
  issue_loads(Wb, Gb, bi * TS, bj * TS, 0, tid, rA);

  // ---- folded bwk: bandwidth scale once per block ----
  {
    float cs = 0.f;
    #pragma unroll 8
    for (int p = 0; p < 32; ++p) cs += scs[p * 512 + tid];
    double p1 = (double)cs * (double)cs;
    double p2 = (tid < 256) ? ssp[tid] : 0.0;
    #pragma unroll
    for (int off = 32; off > 0; off >>= 1) {
      p1 += __shfl_xor(p1, off);
      p2 += __shfl_xor(p2, off);
    }
    if (lane == 0) { pred[wid] = p1; pred2[wid] = p2; }
    __syncthreads();
    if (tid == 0) {
      double s2 = 0.0, ss = 0.0;
      #pragma unroll
      for (int k = 0; k < 8; ++k) { s2 += pred[k]; ss += pred2[k]; }
      double sum_d2 = 2.0 * 8192.0 * ss - 2.0 * s2;
      double bw = sum_d2 / (8192.0 * 8191.0) / 4.0;
      sS4 = (float)(1.4426950408889634 / (bw * 16.0));
    }
    __syncthreads();
  }
  const float s4 = sS4;

  for (int t = s; t < T; t += 32) {
    const int i0 = bi * TS;
    const int j0 = bj * TS;
    // next tile coords (for cross-tile prefetch at the last K-step)
    const int tn = t + 32;
    const bool hasNext = tn < T;
    const int bin = hasNext ? rstart + (tn % 11) : bi;
    const int bjn = hasNext ? cstart + (tn / 11) : bj;

    f32x4 accW[6][3], accG[6][3];
    #pragma unroll
    for (int m = 0; m < 6; ++m)
      #pragma unroll
      for (int n = 0; n < 3; ++n) { accW[m][n] = (f32x4)0.0f; accG[m][n] = (f32x4)0.0f; }

    // K-loop: reg-staged double-buffer, lgkm-only barriers (R13-verified)
    #pragma unroll
    for (int st2 = 0; st2 < 4; ++st2) {
      const int st = st2 * 2;
      write_lds(tid, rA, lds[0]);                      // auto counted-vmcnt for rA
      issue_loads(Wb, Gb, i0, j0, st + 1, tid, rB);
      __builtin_amdgcn_sched_barrier(0);
      BAR_LGKM();
      gram_pass(lds[0], lds[0] + 12288, wr, wc, lr, g, accW);
      gram_pass(lds[0] + 24576, lds[0] + 36864, wr, wc, lr, g, accG);
      write_lds(tid, rB, lds[1]);
      if (st + 2 < 8) {
        issue_loads(Wb, Gb, i0, j0, st + 2, tid, rA);
      } else if (hasNext) {
        issue_loads(Wb, Gb, bin * TS, bjn * TS, 0, tid, rA);  // next tile step 0
      }
      __builtin_amdgcn_sched_barrier(0);
      BAR_LGKM();
      gram_pass(lds[1], lds[1] + 12288, wr, wc, lr, g, accW);
      gram_pass(lds[1] + 24576, lds[1] + 36864, wr, wc, lr, g, accG);
    }

    // ---- per-tile epilogue ----
    __syncthreads();                 // compute done; L free from previous tile
    if (tid < 384) L[tid] = 0.f;

    float rjW[3], rjG[3], mjf[3];
    #pragma unroll
    for (int n = 0; n < 3; ++n) {
      const int j = j0 + wc * 48 + n * 16 + lr;
      rjW[n] = sqbW[j]; rjG[n] = sqbG[j];
      mjf[n] = (j < NROW) ? 1.f : 0.f;
    }

    float rsW[6][4], rsG[6][4];
    float p_loc = 0.f;

    #pragma unroll
    for (int m = 0; m < 6; ++m) {
      const int ib = i0 + wr * 96 + m * 16 + g * 4;
      float riW[4], riG[4], mif[4];
      #pragma unroll
      for (int e = 0; e < 4; ++e) {
        riW[e] = sqbW[ib + e]; riG[e] = sqbG[ib + e];
        mif[e] = (ib + e < NROW) ? 1.f : 0.f;
      }
      #pragma unroll
      for (int e = 0; e < 4; ++e) { rsW[m][e] = 0.f; rsG[m][e] = 0.f; }
      #pragma unroll
      for (int n = 0; n < 3; ++n) {
        #pragma unroll
        for (int e = 0; e < 4; ++e) {
          const float mk = mif[e] * mjf[n];
          float d2w = fmaxf(riW[e] + rjW[n] - 2.f * accW[m][n][e], 0.f);
          float yw = fexp2(-d2w * s4);
          float yw2 = yw * yw, yw4 = yw2 * yw2, yw8 = yw4 * yw4, yw16 = yw8 * yw8;
          float kw = (yw + yw2 + yw4 + yw8 + yw16) * mk;
          float d2g = fmaxf(riG[e] + rjG[n] - 2.f * accG[m][n][e], 0.f);
          float yg = fexp2(-d2g * s4);
          float yg2 = yg * yg, yg4 = yg2 * yg2, yg8 = yg4 * yg4, yg16 = yg8 * yg8;
          float kg = (yg + yg2 + yg4 + yg8 + yg16) * mk;
          p_loc = fmaf(kw, kg, p_loc);
          rsW[m][e] += kw; rsG[m][e] += kg;
        }
      }
    }

    __syncthreads();   // L zeroing visible before atomics

    // row sums -> LDS (butterfly over 16 column-lanes, then 4-way LDS atomic)
    #pragma unroll
    for (int m = 0; m < 6; ++m)
      #pragma unroll
      for (int e = 0; e < 4; ++e) {
        float xv = rsW[m][e], yv = rsG[m][e];
        xv += __shfl_xor(xv, 1); xv += __shfl_xor(xv, 2); xv += __shfl_xor(xv, 4); xv += __shfl_xor(xv, 8);
        yv += __shfl_xor(yv, 1); yv += __shfl_xor(yv, 2); yv += __shfl_xor(yv, 4); yv += __shfl_xor(yv, 8);
        if (lr == 0) {
          const int rloc = wr * 96 + m * 16 + g * 4 + e;   // 0..191
          atomicAdd(&L[rloc], xv);
          atomicAdd(&L[192 + rloc], yv);
        }
      }

    // P: f32 wave butterfly -> pred
    #pragma unroll
    for (int off = 32; off > 0; off >>= 1) p_loc += __shfl_xor(p_loc, off);
    if (lane == 0) pred[wid] = (double)p_loc;
    __syncthreads();

    // plain coalesced partial stores (each (bi,bj) written by exactly one block)
    const int tslot = bi * NT + bj;
    if (tid < 192) {
      PU[tslot * 192 + tid] = L[tid];
      PV[tslot * 192 + tid] = L[192 + tid];
    }
    if (tid == 0) {
      double ps = 0.0;
      #pragma unroll
      for (int k = 0; k < 8; ++k) ps += pred[k];
      PSL[tslot] = ps;
    }

    bi = bin; bj = bjn;   // advance (rA already holds next tile's step-0 data)
  }
}

// ---- finalize (single launch): u,v from partials; loss
__global__ __launch_bounds__(1024) void finalize(
    const float* __restrict__ PU, const float* __restrict__ PV,
    const double* __restrict__ PSL, float* __restrict__ out)
{
  __shared__ double r0[1024], r1[1024], r2[1024], r3[1024];
  const int t = threadIdx.x;
  double uv = 0.0, su = 0.0, sv = 0.0, pp = 0.0;
  for (int i = t; i < NPAD; i += 1024) {
    const int b = i / 192, ii = i - b * 192;
    double uu = 0.0, vv = 0.0;
    #pragma unroll
    for (int k = 0; k < NT; ++k) {
      uu += (double)PU[(b * NT + k) * 192 + ii];
      vv += (double)PV[(b * NT + k) * 192 + ii];
    }
    uv += uu * vv; su += uu; sv += vv;
  }
  if (t < 484) pp = PSL[t];
  r0[t] = uv; r1[t] = su; r2[t] = sv; r3[t] = pp;
  __syncthreads();
  for (int k = 512; k > 0; k >>= 1) {
    if (t < k) { r0[t] += r0[t + k]; r1[t] += r1[t + k]; r2[t] += r2[t + k]; r3[t] += r3[t + k]; }
    __syncthreads();
  }
  if (t == 0) {
    const double n = 4096.0;
    double hsic = r3[0] - (2.0 / n) * r0[0] + (r1[0] * r2[0]) / (n * n);
    out[0] = (float)(-hsic / ((n - 1.0) * (n - 1.0)));
  }
}

extern "C" void kernel_launch(void* const* d_in, const int* in_sizes, int n_in,
                              void* d_out, int out_size, void* d_ws, size_t ws_size,
                              hipStream_t stream) {
  const float* W = (const float*)d_in[0];
  const float* G = (const float*)d_in[1];
  char* ws = (char*)d_ws;
  unsigned char* Wb = (unsigned char*)(ws + WB_OFF);
  unsigned char* Gb = (unsigned char*)(ws + GB_OFF);
  float* sqbW = (float*)(ws + SQBW_OFF);
  float* sqbG = (float*)(ws + SQBG_OFF);
  float* scs = (float*)(ws + SCS_OFF);
  double* ssp = (double*)(ws + SSP_OFF);
  float* PU = (float*)(ws + PU_OFF);
  float* PV = (float*)(ws + PV_OFF);
  double* PSL = (double*)(ws + PSL_OFF);

  hipMemsetAsync(ws + ZERO_BEG, 0, ZERO_END - ZERO_BEG, stream);

  prep_rows<<<2112, 256, 0, stream>>>(W, G, Wb, Gb, sqbW, sqbG, ssp, scs);
  gram_kernel<<<256, 512, 0, stream>>>(Wb, Gb, sqbW, sqbG, scs, ssp, PU, PV, PSL);
  finalize<<<1, 1024, 0, stream>>>(PU, PV, PSL, (float*)d_out);
}

// Round 15
// 58.828 us; speedup vs baseline: 2.1779x; 2.1779x over previous
//
#include <hip/hip_runtime.h>
#include <stdint.h>

typedef __attribute__((ext_vector_type(4))) float f32x4;
typedef __attribute__((ext_vector_type(2))) unsigned int u32x2;
typedef __attribute__((ext_vector_type(4))) unsigned int u32x4;

#define NROW 4096
#define DDIM 512
#define NT   22            // tiles per dim
#define TS   192
#define NPAD 4224

// ---------------- ws layout (bytes) ----------------
#define WB_OFF   0u          // fp8[4224*512] = 2162688
#define GB_OFF   2162688u    // fp8[4224*512]
#define SQBW_OFF 4325376u    // float[4224]
#define SQBG_OFF 4342272u    // float[4224]
#define SCS_OFF  4359168u    // float[32][512] (zeroed)
#define SSP_OFF  4424704u    // double[256]    (zeroed)
#define PU_OFF   4426752u    // float[22][22][192] = 371712 (fully written)
#define PV_OFF   4798464u    // float[22][22][192]
#define PSL_OFF  5170176u    // double[253]    (fully written)
#define ZERO_BEG SCS_OFF
#define ZERO_END (SSP_OFF + 2048u)

// raw barrier: drains LDS ops only — in-flight global loads stay in flight (T4)
#define BAR_LGKM() asm volatile("s_waitcnt lgkmcnt(0)\n\ts_barrier" ::: "memory")

__device__ __forceinline__ void atomAddF64(double* p, double v) {
  __hip_atomic_fetch_add(p, v, __ATOMIC_RELAXED, __HIP_MEMORY_SCOPE_AGENT);
}
__device__ __forceinline__ void atomAddF32(float* p, float v) {
  __hip_atomic_fetch_add(p, v, __ATOMIC_RELAXED, __HIP_MEMORY_SCOPE_AGENT);
}

// fast 2^x (x <= 0, modest |x|; denormal flush harmless) — validated R11
__device__ __forceinline__ float fexp2(float x) {
  float r;
  asm("v_exp_f32 %0, %1" : "=v"(r) : "v"(x));
  return r;
}

// ---- fp8 e4m3fn helpers ----
__device__ __forceinline__ float fp8dec(unsigned b) {
  unsigned e = (b >> 3) & 15u, m = b & 7u;
  float v = ldexpf((float)(e ? (m | 8u) : m), (int)e - 10 + (e == 0));
  return (b & 0x80u) ? -v : v;
}

__device__ __forceinline__ unsigned f2fp8_manual(float f) {
  unsigned u = __float_as_uint(f);
  unsigned s = (u >> 24) & 0x80u;
  float a = __uint_as_float(u & 0x7FFFFFFFu);
  if (a >= 448.f) return s | 0x7Eu;
  if (a >= 0.015625f) {
    unsigned au = __float_as_uint(a);
    au += 0x7FFFFu + ((au >> 20) & 1u);
    unsigned e = (au >> 23) - 120u;
    unsigned m = (au >> 20) & 7u;
    if (e >= 16u) return s | 0x7Eu;
    return s | (e << 3) | m;
  }
  int q = (int)rintf(a * 512.f);
  return s | (unsigned)q;
}

#if __has_builtin(__builtin_amdgcn_cvt_pk_fp8_f32)
__device__ __forceinline__ unsigned pack4_fp8(float x0, float x1, float x2, float x3) {
  unsigned p = __builtin_amdgcn_cvt_pk_fp8_f32(x0, x1, 0, false);
  p = __builtin_amdgcn_cvt_pk_fp8_f32(x2, x3, p, true);
  return p;
}
#else
__device__ __forceinline__ unsigned pack4_fp8(float x0, float x1, float x2, float x3) {
  return f2fp8_manual(x0) | (f2fp8_manual(x1) << 8) |
         (f2fp8_manual(x2) << 16) | (f2fp8_manual(x3) << 24);
}
#endif

// ---- prep (R10/R11-validated LUT version): 16 rows/block; fp32->fp8;
// fp8-consistent row sumsq via LDS LUT; register col sums (4x fewer atomics)
__global__ __launch_bounds__(256) void prep_rows(
    const float* __restrict__ W, const float* __restrict__ G,
    unsigned char* __restrict__ Wb, unsigned char* __restrict__ Gb,
    float* __restrict__ sqbW, float* __restrict__ sqbG,
    double* __restrict__ ssp, float* __restrict__ scs)
{
  __shared__ float colsLDS[4][512];
  __shared__ float lut2[256];          // dec(byte)^2
  const int bid = blockIdx.x;
  const int w = threadIdx.x >> 6;
  const int l = threadIdx.x & 63;

  if (bid >= 512) {                    // pad-row zeroing: 16 blocks x 16 rows
    #pragma unroll
    for (int it = 0; it < 4; ++it) {
      const int pr = (bid - 512) * 16 + it * 4 + w;   // 0..255
      const bool isG = pr >= 128;
      const int row = NROW + (pr & 127);
      unsigned char* dst = (isG ? Gb : Wb) + (size_t)row * DDIM;
      *(u32x2*)(dst + l * 8) = (u32x2){0u, 0u};
      if (l == 0) (isG ? sqbG : sqbW)[row] = 0.f;
    }
    return;
  }

  {
    const float d = fp8dec(threadIdx.x);
    lut2[threadIdx.x] = d * d;
  }
  __syncthreads();

  float colr[8] = {0.f,0.f,0.f,0.f,0.f,0.f,0.f,0.f};
  float s32 = 0.f;

  #pragma unroll
  for (int it = 0; it < 4; ++it) {
    const int row = bid * 16 + it * 4 + w;   // 0..8191
    const float* src; unsigned char* dst; float* sqb; int r;
    if (row < NROW) { src = W + (size_t)row * DDIM; dst = Wb + (size_t)row * DDIM; sqb = sqbW; r = row; }
    else            { src = G + (size_t)(row - NROW) * DDIM; dst = Gb + (size_t)(row - NROW) * DDIM; sqb = sqbG; r = row - NROW; }
    const f32x4 a = *(const f32x4*)(src + l * 8);
    const f32x4 b = *(const f32x4*)(src + l * 8 + 4);
    const unsigned p0 = pack4_fp8(a[0], a[1], a[2], a[3]);
    const unsigned p1 = pack4_fp8(b[0], b[1], b[2], b[3]);
    *(u32x2*)(dst + l * 8) = (u32x2){p0, p1};

    float sb = 0.f;
    #pragma unroll
    for (int j = 0; j < 4; ++j) {
      s32 += a[j] * a[j] + b[j] * b[j];
      colr[j] += a[j]; colr[4 + j] += b[j];
      sb += lut2[(p0 >> (8 * j)) & 0xFFu] + lut2[(p1 >> (8 * j)) & 0xFFu];
    }
    #pragma unroll
    for (int off = 32; off > 0; off >>= 1) sb += __shfl_down(sb, off);
    if (l == 0) sqb[r] = sb;
  }

  // col partials: one LDS write per thread, 512 f32 atomics per block
  #pragma unroll
  for (int j = 0; j < 8; ++j) colsLDS[w][l * 8 + j] = colr[j];
  __syncthreads();
  {
    const int c = threadIdx.x;
    atomAddF32(&scs[(bid & 31) * 512 + c],
               colsLDS[0][c] + colsLDS[1][c] + colsLDS[2][c] + colsLDS[3][c]);
    const int c2 = c + 256;
    atomAddF32(&scs[(bid & 31) * 512 + c2],
               colsLDS[0][c2] + colsLDS[1][c2] + colsLDS[2][c2] + colsLDS[3][c2]);
  }
  #pragma unroll
  for (int off = 32; off > 0; off >>= 1) s32 += __shfl_down(s32, off);
  if (l == 0) atomAddF64(&ssp[bid & 255], (double)s32);
}

// ---- issue 6 global_load_dwordx4 for one BK=64 step into regs (T14 issue-early).
__device__ __forceinline__ void issue_loads(
    const unsigned char* __restrict__ Wb, const unsigned char* __restrict__ Gb,
    int i0, int j0, int st, int tid, u32x4 r[6])
{
  const int kb = st * 64;
  #pragma unroll
  for (int q = 0; q < 6; ++q) {
    const int slot = q * 512 + tid;   // 0..3071, 16B each; panels of 768 slots
    int p;
    if (q == 0) p = 0;
    else if (q == 1) p = (slot < 768) ? 0 : 1;
    else if (q == 2) p = 1;
    else if (q == 3) p = 2;
    else if (q == 4) p = (slot < 2304) ? 2 : 3;
    else p = 3;
    const unsigned char* mat = (p < 2) ? Wb : Gb;
    const int rb = (p & 1) ? j0 : i0;
    const int rr = slot - p * 768;
    const int row = rr >> 2;
    const int c = (rr & 3) ^ ((row >> 1) & 3);
    r[q] = *(const u32x4*)(mat + (size_t)(rb + row) * 512 + kb + c * 16);
  }
}

// ---- write staged regs to LDS (linear slots; ds_write_b128)
__device__ __forceinline__ void write_lds(int tid, const u32x4 r[6],
                                          unsigned char* __restrict__ buf)
{
  #pragma unroll
  for (int q = 0; q < 6; ++q) {
    const int slot = q * 512 + tid;
    *(u32x4*)(buf + slot * 16) = r[q];
  }
}

// ---- one K=64 step (2 x K=32 MFMA) for one gram (R6 verbatim)
__device__ __forceinline__ void gram_pass(
    const unsigned char* __restrict__ A, const unsigned char* __restrict__ B,
    int wr, int wc, int lr, int g, f32x4 acc[6][3])
{
  #pragma unroll
  for (int kk = 0; kk < 2; ++kk) {
    long long a[6], b[3];
    #pragma unroll
    for (int m = 0; m < 6; ++m) {
      const int row = wr * 96 + m * 16 + lr;
      const int off = row * 64 + (((kk * 2 + (g >> 1)) ^ ((row >> 1) & 3)) << 4) + ((g & 1) << 3);
      a[m] = *(const long long*)(A + off);
    }
    #pragma unroll
    for (int n = 0; n < 3; ++n) {
      const int row = wc * 48 + n * 16 + lr;
      const int off = row * 64 + (((kk * 2 + (g >> 1)) ^ ((row >> 1) & 3)) << 4) + ((g & 1) << 3);
      b[n] = *(const long long*)(B + off);
    }
    __builtin_amdgcn_s_setprio(1);
    #pragma unroll
    for (int m = 0; m < 6; ++m)
      #pragma unroll
      for (int n = 0; n < 3; ++n)
        acc[m][n] = __builtin_amdgcn_mfma_f32_16x16x32_fp8_fp8(a[m], b[n], acc[m][n], 0, 0, 0);
    __builtin_amdgcn_s_setprio(0);
  }
}

// ---- main (R13 verbatim): 192^2 upper-tri tiles, reg-staged counted-vmcnt pipeline
__global__ __launch_bounds__(512, 2) void gram_kernel(
    const unsigned char* __restrict__ Wb, const unsigned char* __restrict__ Gb,
    const float* __restrict__ sqbW, const float* __restrict__ sqbG,
    const float* __restrict__ scs, const double* __restrict__ ssp,
    float* __restrict__ PU, float* __restrict__ PV, double* __restrict__ PSL)
{
  __shared__ __align__(16) unsigned char lds[2][49152];  // dbuf: AW|BW|AG|BG each
  __shared__ float L[768];   // rowW|rowG|colW|colG reduction arrays
  __shared__ double pred[8], pred2[8];
  __shared__ float sS4;

  // T1: bijective XCD-chunked swizzle (nwg=253: q=31, r=5)
  const int orig = blockIdx.x;
  const int xcd = orig & 7;
  const int idx = orig >> 3;
  const int swz = (xcd < 5 ? xcd * 32 : 5 * 32 + (xcd - 5) * 31) + idx;

  // decode upper-triangular tile index: 0 <= bi <= bj < 22
  int t = swz;
  int bi = 0;
  while (t >= NT - bi) { t -= NT - bi; ++bi; }
  const int bj = bi + t;
  const bool offdiag = (bi != bj);

  const int tid = threadIdx.x;
  const int lane = tid & 63;
  const int wid = tid >> 6;
  const int wr = wid >> 2;      // 0..1  (96-row half)
  const int wc = wid & 3;       // 0..3  (48-col quarter)
  const int i0 = bi * TS;
  const int j0 = bj * TS;
  const int g = lane >> 4;
  const int lr = lane & 15;

  f32x4 accW[6][3], accG[6][3];
  #pragma unroll
  for (int m = 0; m < 6; ++m)
    #pragma unroll
    for (int n = 0; n < 3; ++n) { accW[m][n] = (f32x4)0.0f; accG[m][n] = (f32x4)0.0f; }

  // ---- K-loop: reg-staged double-buffer, ONE lgkm-only barrier per step.
  u32x4 rA[6], rB[6];
  issue_loads(Wb, Gb, i0, j0, 0, tid, rA);

  #pragma unroll
  for (int st2 = 0; st2 < 4; ++st2) {
    const int st = st2 * 2;
    write_lds(tid, rA, lds[0]);                      // auto counted-vmcnt for rA
    issue_loads(Wb, Gb, i0, j0, st + 1, tid, rB);
    __builtin_amdgcn_sched_barrier(0);
    BAR_LGKM();                                      // no vmcnt drain: rB stays in flight
    gram_pass(lds[0], lds[0] + 12288, wr, wc, lr, g, accW);
    gram_pass(lds[0] + 24576, lds[0] + 36864, wr, wc, lr, g, accG);
    write_lds(tid, rB, lds[1]);
    if (st + 2 < 8) issue_loads(Wb, Gb, i0, j0, st + 2, tid, rA);
    __builtin_amdgcn_sched_barrier(0);
    BAR_LGKM();
    gram_pass(lds[1], lds[1] + 12288, wr, wc, lr, g, accW);
    gram_pass(lds[1] + 24576, lds[1] + 36864, wr, wc, lr, g, accG);
  }
  __syncthreads();

  // ---- folded bwk: bandwidth scale computed redundantly per block ----
  {
    float cs = 0.f;
    #pragma unroll 8
    for (int p = 0; p < 32; ++p) cs += scs[p * 512 + tid];
    double p1 = (double)cs * (double)cs;
    double p2 = (tid < 256) ? ssp[tid] : 0.0;
    #pragma unroll
    for (int off = 32; off > 0; off >>= 1) {
      p1 += __shfl_xor(p1, off);
      p2 += __shfl_xor(p2, off);
    }
    if (lane == 0) { pred[wid] = p1; pred2[wid] = p2; }
    __syncthreads();
    if (tid == 0) {
      double s2 = 0.0, ss = 0.0;
      #pragma unroll
      for (int k = 0; k < 8; ++k) { s2 += pred[k]; ss += pred2[k]; }
      double sum_d2 = 2.0 * 8192.0 * ss - 2.0 * s2;
      double bw = sum_d2 / (8192.0 * 8191.0) / 4.0;
      sS4 = (float)(1.4426950408889634 / (bw * 16.0));
    }
    __syncthreads();
  }
  const float s4 = sS4;

  // zero ALL 768 reduction slots (512 threads: two passes)
  L[tid] = 0.f;
  if (tid < 256) L[512 + tid] = 0.f;

  // ---- epilogue: kernel values (f32, fexp2 — validated R11) ----
  float rjW[3], rjG[3], mjf[3];
  #pragma unroll
  for (int n = 0; n < 3; ++n) {
    const int j = j0 + wc * 48 + n * 16 + lr;
    rjW[n] = sqbW[j]; rjG[n] = sqbG[j];
    mjf[n] = (j < NROW) ? 1.f : 0.f;
  }

  float csW[3] = {0.f, 0.f, 0.f}, csG[3] = {0.f, 0.f, 0.f};
  float rsW[6][4], rsG[6][4];
  float p_loc = 0.f;

  #pragma unroll
  for (int m = 0; m < 6; ++m) {
    const int ib = i0 + wr * 96 + m * 16 + g * 4;
    float riW[4], riG[4], mif[4];
    #pragma unroll
    for (int e = 0; e < 4; ++e) {
      riW[e] = sqbW[ib + e]; riG[e] = sqbG[ib + e];
      mif[e] = (ib + e < NROW) ? 1.f : 0.f;
    }
    #pragma unroll
    for (int e = 0; e < 4; ++e) { rsW[m][e] = 0.f; rsG[m][e] = 0.f; }
    #pragma unroll
    for (int n = 0; n < 3; ++n) {
      #pragma unroll
      for (int e = 0; e < 4; ++e) {
        const float mk = mif[e] * mjf[n];
        float d2w = fmaxf(riW[e] + rjW[n] - 2.f * accW[m][n][e], 0.f);
        float yw = fexp2(-d2w * s4);
        float yw2 = yw * yw, yw4 = yw2 * yw2, yw8 = yw4 * yw4, yw16 = yw8 * yw8;
        float kw = (yw + yw2 + yw4 + yw8 + yw16) * mk;
        float d2g = fmaxf(riG[e] + rjG[n] - 2.f * accG[m][n][e], 0.f);
        float yg = fexp2(-d2g * s4);
        float yg2 = yg * yg, yg4 = yg2 * yg2, yg8 = yg4 * yg4, yg16 = yg8 * yg8;
        float kg = (yg + yg2 + yg4 + yg8 + yg16) * mk;
        p_loc = fmaf(kw, kg, p_loc);
        rsW[m][e] += kw; rsG[m][e] += kg;
        csW[n] += kw; csG[n] += kg;
      }
    }
  }

  __syncthreads();   // L zeroing visible

  // row sums -> LDS (butterfly over the 16 column-lanes, then 4-way LDS atomic)
  #pragma unroll
  for (int m = 0; m < 6; ++m)
    #pragma unroll
    for (int e = 0; e < 4; ++e) {
      float x = rsW[m][e], y = rsG[m][e];
      x += __shfl_xor(x, 1); x += __shfl_xor(x, 2); x += __shfl_xor(x, 4); x += __shfl_xor(x, 8);
      y += __shfl_xor(y, 1); y += __shfl_xor(y, 2); y += __shfl_xor(y, 4); y += __shfl_xor(y, 8);
      if (lr == 0) {
        const int rloc = wr * 96 + m * 16 + g * 4 + e;   // 0..191
        atomicAdd(&L[rloc], x);
        atomicAdd(&L[192 + rloc], y);
      }
    }

  // col sums -> LDS (butterfly over g-groups, then 2-way LDS atomic)
  if (offdiag) {
    #pragma unroll
    for (int n = 0; n < 3; ++n) {
      float x = csW[n], y = csG[n];
      x += __shfl_xor(x, 16); x += __shfl_xor(x, 32);
      y += __shfl_xor(y, 16); y += __shfl_xor(y, 32);
      if (g == 0) {
        const int cloc = wc * 48 + n * 16 + lr;          // 0..191
        atomicAdd(&L[384 + cloc], x);
        atomicAdd(&L[576 + cloc], y);
      }
    }
  }

  __syncthreads();

  // plain coalesced partial stores (no global atomics)
  if (tid < 192) {
    PU[(bi * NT + bj) * 192 + tid] = L[tid];
    PV[(bi * NT + bj) * 192 + tid] = L[192 + tid];
    if (offdiag) {
      PU[(bj * NT + bi) * 192 + tid] = L[384 + tid];
      PV[(bj * NT + bi) * 192 + tid] = L[576 + tid];
    }
  }

  // P: f32 wave butterfly -> f64 block sum -> one plain store per tile
  #pragma unroll
  for (int off = 32; off > 0; off >>= 1) p_loc += __shfl_xor(p_loc, off);
  if (lane == 0) pred[wid] = (double)p_loc;
  __syncthreads();
  if (tid == 0) {
    double ps = 0.0;
    #pragma unroll
    for (int k = 0; k < 8; ++k) ps += pred[k];
    PSL[swz] = offdiag ? 2.0 * ps : ps;
  }
}

// ---- finalize (single launch): u,v from partials; loss
__global__ __launch_bounds__(1024) void finalize(
    const float* __restrict__ PU, const float* __restrict__ PV,
    const double* __restrict__ PSL, float* __restrict__ out)
{
  __shared__ double r0[1024], r1[1024], r2[1024], r3[1024];
  const int t = threadIdx.x;
  double uv = 0.0, su = 0.0, sv = 0.0, pp = 0.0;
  for (int i = t; i < NPAD; i += 1024) {
    const int b = i / 192, ii = i - b * 192;
    double uu = 0.0, vv = 0.0;
    #pragma unroll
    for (int k = 0; k < NT; ++k) {
      uu += (double)PU[(b * NT + k) * 192 + ii];
      vv += (double)PV[(b * NT + k) * 192 + ii];
    }
    uv += uu * vv; su += uu; sv += vv;
  }
  if (t < 253) pp = PSL[t];
  r0[t] = uv; r1[t] = su; r2[t] = sv; r3[t] = pp;
  __syncthreads();
  for (int k = 512; k > 0; k >>= 1) {
    if (t < k) { r0[t] += r0[t + k]; r1[t] += r1[t + k]; r2[t] += r2[t + k]; r3[t] += r3[t + k]; }
    __syncthreads();
  }
  if (t == 0) {
    const double n = 4096.0;
    double hsic = r3[0] - (2.0 / n) * r0[0] + (r1[0] * r2[0]) / (n * n);
    out[0] = (float)(-hsic / ((n - 1.0) * (n - 1.0)));
  }
}

extern "C" void kernel_launch(void* const* d_in, const int* in_sizes, int n_in,
                              void* d_out, int out_size, void* d_ws, size_t ws_size,
                              hipStream_t stream) {
  const float* W = (const float*)d_in[0];
  const float* G = (const float*)d_in[1];
  char* ws = (char*)d_ws;
  unsigned char* Wb = (unsigned char*)(ws + WB_OFF);
  unsigned char* Gb = (unsigned char*)(ws + GB_OFF);
  float* sqbW = (float*)(ws + SQBW_OFF);
  float* sqbG = (float*)(ws + SQBG_OFF);
  float* scs = (float*)(ws + SCS_OFF);
  double* ssp = (double*)(ws + SSP_OFF);
  float* PU = (float*)(ws + PU_OFF);
  float* PV = (float*)(ws + PV_OFF);
  double* PSL = (double*)(ws + PSL_OFF);

  hipMemsetAsync(ws + ZERO_BEG, 0, ZERO_END - ZERO_BEG, stream);

  prep_rows<<<528, 256, 0, stream>>>(W, G, Wb, Gb, sqbW, sqbG, ssp, scs);
  gram_kernel<<<253, 512, 0, stream>>>(Wb, Gb, sqbW, sqbG, scs, ssp, PU, PV, PSL);
  finalize<<<1, 1024, 0, stream>>>(PU, PV, PSL, (float*)d_out);
}

// Round 16
// 58.771 us; speedup vs baseline: 2.1800x; 1.0010x over previous
//
#include <hip/hip_runtime.h>
#include <stdint.h>

typedef __attribute__((ext_vector_type(4))) float f32x4;
typedef __attribute__((ext_vector_type(2))) unsigned int u32x2;
typedef __attribute__((ext_vector_type(4))) unsigned int u32x4;

#define NROW 4096
#define DDIM 512
#define NT   22            // tiles per dim
#define TS   192
#define NPAD 4224

// ---------------- ws layout (bytes) ----------------
// Wb/Gb are PACKED: [block(22)][st(8)][row(192)][64B], swizzle pre-baked = LDS image.
#define WB_OFF   0u          // fp8 packed [22*8*12288] = 2162688
#define GB_OFF   2162688u    // fp8 packed
#define SQBW_OFF 4325376u    // float[4224]
#define SQBG_OFF 4342272u    // float[4224]
#define SCS_OFF  4359168u    // float[32][512] (zeroed)
#define SSP_OFF  4424704u    // double[256]    (zeroed)
#define PU_OFF   4426752u    // float[22][22][192] = 371712 (fully written)
#define PV_OFF   4798464u    // float[22][22][192]
#define PSL_OFF  5170176u    // double[253]    (fully written)
#define ZERO_BEG SCS_OFF
#define ZERO_END (SSP_OFF + 2048u)

// raw barrier: drains LDS ops only — in-flight global loads stay in flight (T4)
#define BAR_LGKM() asm volatile("s_waitcnt lgkmcnt(0)\n\ts_barrier" ::: "memory")

__device__ __forceinline__ void atomAddF64(double* p, double v) {
  __hip_atomic_fetch_add(p, v, __ATOMIC_RELAXED, __HIP_MEMORY_SCOPE_AGENT);
}
__device__ __forceinline__ void atomAddF32(float* p, float v) {
  __hip_atomic_fetch_add(p, v, __ATOMIC_RELAXED, __HIP_MEMORY_SCOPE_AGENT);
}

// fast 2^x (x <= 0, modest |x|; denormal flush harmless) — validated R11
__device__ __forceinline__ float fexp2(float x) {
  float r;
  asm("v_exp_f32 %0, %1" : "=v"(r) : "v"(x));
  return r;
}

// ---- fp8 e4m3fn helpers ----
__device__ __forceinline__ float fp8dec(unsigned b) {
  unsigned e = (b >> 3) & 15u, m = b & 7u;
  float v = ldexpf((float)(e ? (m | 8u) : m), (int)e - 10 + (e == 0));
  return (b & 0x80u) ? -v : v;
}

__device__ __forceinline__ unsigned f2fp8_manual(float f) {
  unsigned u = __float_as_uint(f);
  unsigned s = (u >> 24) & 0x80u;
  float a = __uint_as_float(u & 0x7FFFFFFFu);
  if (a >= 448.f) return s | 0x7Eu;
  if (a >= 0.015625f) {
    unsigned au = __float_as_uint(a);
    au += 0x7FFFFu + ((au >> 20) & 1u);
    unsigned e = (au >> 23) - 120u;
    unsigned m = (au >> 20) & 7u;
    if (e >= 16u) return s | 0x7Eu;
    return s | (e << 3) | m;
  }
  int q = (int)rintf(a * 512.f);
  return s | (unsigned)q;
}

#if __has_builtin(__builtin_amdgcn_cvt_pk_fp8_f32)
__device__ __forceinline__ unsigned pack4_fp8(float x0, float x1, float x2, float x3) {
  unsigned p = __builtin_amdgcn_cvt_pk_fp8_f32(x0, x1, 0, false);
  p = __builtin_amdgcn_cvt_pk_fp8_f32(x2, x3, p, true);
  return p;
}
#else
__device__ __forceinline__ unsigned pack4_fp8(float x0, float x1, float x2, float x3) {
  return f2fp8_manual(x0) | (f2fp8_manual(x1) << 8) |
         (f2fp8_manual(x2) << 16) | (f2fp8_manual(x3) << 24);
}
#endif

// ---- prep: 16 rows/block; fp32->fp8 into PACKED layout; LUT row sumsq; col sums
__global__ __launch_bounds__(256) void prep_rows(
    const float* __restrict__ W, const float* __restrict__ G,
    unsigned char* __restrict__ Wb, unsigned char* __restrict__ Gb,
    float* __restrict__ sqbW, float* __restrict__ sqbG,
    double* __restrict__ ssp, float* __restrict__ scs)
{
  __shared__ float colsLDS[4][512];
  __shared__ float lut2[256];          // dec(byte)^2
  const int bid = blockIdx.x;
  const int w = threadIdx.x >> 6;
  const int l = threadIdx.x & 63;

  if (bid >= 512) {                    // pad-row zeroing: 16 blocks x 16 rows
    #pragma unroll
    for (int it = 0; it < 4; ++it) {
      const int pr = (bid - 512) * 16 + it * 4 + w;   // 0..255
      const bool isG = pr >= 128;
      const int row = NROW + (pr & 127);              // 4096..4223 (all in block 21)
      const int rloc = row - 21 * 192;                // 64..191
      unsigned char* base = (isG ? Gb : Wb);
      // zero the row's 8B chunk in its packed st-block (swizzle irrelevant for zeros)
      const int st = l >> 3;
      unsigned char* dst = base + ((size_t)(21 * 8 + st)) * 12288 + rloc * 64 + (l & 7) * 8;
      *(u32x2*)dst = (u32x2){0u, 0u};
      if (l == 0) (isG ? sqbG : sqbW)[row] = 0.f;
    }
    return;
  }

  {
    const float d = fp8dec(threadIdx.x);
    lut2[threadIdx.x] = d * d;
  }
  __syncthreads();

  float colr[8] = {0.f,0.f,0.f,0.f,0.f,0.f,0.f,0.f};
  float s32 = 0.f;

  #pragma unroll
  for (int it = 0; it < 4; ++it) {
    const int row = bid * 16 + it * 4 + w;   // 0..8191
    const float* src; unsigned char* base; float* sqb; int r;
    if (row < NROW) { src = W + (size_t)row * DDIM; base = Wb; sqb = sqbW; r = row; }
    else            { src = G + (size_t)(row - NROW) * DDIM; base = Gb; sqb = sqbG; r = row - NROW; }
    const f32x4 a = *(const f32x4*)(src + l * 8);
    const f32x4 b = *(const f32x4*)(src + l * 8 + 4);
    const unsigned p0 = pack4_fp8(a[0], a[1], a[2], a[3]);
    const unsigned p1 = pack4_fp8(b[0], b[1], b[2], b[3]);

    // packed dst: thread covers k = l*8 .. l*8+7 (one 8B half-slot)
    const int br = r / 192;
    const int rloc = r - br * 192;
    const int st = l >> 3;                       // (l*8)/64
    const int c_src = (l & 7) >> 1;              // ((l*8)%64)/16
    const int c_dst = c_src ^ ((rloc >> 1) & 3); // pre-baked swizzle
    unsigned char* dst = base + ((size_t)(br * 8 + st)) * 12288
                       + rloc * 64 + c_dst * 16 + (l & 1) * 8;
    *(u32x2*)dst = (u32x2){p0, p1};

    float sb = 0.f;
    #pragma unroll
    for (int j = 0; j < 4; ++j) {
      s32 += a[j] * a[j] + b[j] * b[j];
      colr[j] += a[j]; colr[4 + j] += b[j];
      sb += lut2[(p0 >> (8 * j)) & 0xFFu] + lut2[(p1 >> (8 * j)) & 0xFFu];
    }
    #pragma unroll
    for (int off = 32; off > 0; off >>= 1) sb += __shfl_down(sb, off);
    if (l == 0) sqb[r] = sb;
  }

  // col partials: one LDS write per thread, 512 f32 atomics per block
  #pragma unroll
  for (int j = 0; j < 8; ++j) colsLDS[w][l * 8 + j] = colr[j];
  __syncthreads();
  {
    const int c = threadIdx.x;
    atomAddF32(&scs[(bid & 31) * 512 + c],
               colsLDS[0][c] + colsLDS[1][c] + colsLDS[2][c] + colsLDS[3][c]);
    const int c2 = c + 256;
    atomAddF32(&scs[(bid & 31) * 512 + c2],
               colsLDS[0][c2] + colsLDS[1][c2] + colsLDS[2][c2] + colsLDS[3][c2]);
  }
  #pragma unroll
  for (int off = 32; off > 0; off >>= 1) s32 += __shfl_down(s32, off);
  if (l == 0) atomAddF64(&ssp[bid & 255], (double)s32);
}

// ---- issue 6 global_load_dwordx4 for one BK=64 step: PACKED source — each wave
// reads 1024 B fully contiguous (dense 128B lines, sequential channels).
__device__ __forceinline__ void issue_loads(
    const unsigned char* __restrict__ Wb, const unsigned char* __restrict__ Gb,
    int bi, int bj, int st, int tid, u32x4 r[6])
{
  #pragma unroll
  for (int q = 0; q < 6; ++q) {
    const int slot = q * 512 + tid;   // 0..3071, 16B each; panels of 768 slots
    int p;
    if (q == 0) p = 0;
    else if (q == 1) p = (slot < 768) ? 0 : 1;
    else if (q == 2) p = 1;
    else if (q == 3) p = 2;
    else if (q == 4) p = (slot < 2304) ? 2 : 3;
    else p = 3;
    const unsigned char* mat = (p < 2) ? Wb : Gb;
    const int blk = (p & 1) ? bj : bi;
    const int rr = slot - p * 768;
    r[q] = *(const u32x4*)(mat + ((size_t)(blk * 8 + st)) * 12288 + rr * 16);
  }
}

// ---- write staged regs to LDS (linear slots; ds_write_b128)
__device__ __forceinline__ void write_lds(int tid, const u32x4 r[6],
                                          unsigned char* __restrict__ buf)
{
  #pragma unroll
  for (int q = 0; q < 6; ++q) {
    const int slot = q * 512 + tid;
    *(u32x4*)(buf + slot * 16) = r[q];
  }
}

// ---- one K=64 step (2 x K=32 MFMA) for one gram (R6 verbatim — LDS image unchanged)
__device__ __forceinline__ void gram_pass(
    const unsigned char* __restrict__ A, const unsigned char* __restrict__ B,
    int wr, int wc, int lr, int g, f32x4 acc[6][3])
{
  #pragma unroll
  for (int kk = 0; kk < 2; ++kk) {
    long long a[6], b[3];
    #pragma unroll
    for (int m = 0; m < 6; ++m) {
      const int row = wr * 96 + m * 16 + lr;
      const int off = row * 64 + (((kk * 2 + (g >> 1)) ^ ((row >> 1) & 3)) << 4) + ((g & 1) << 3);
      a[m] = *(const long long*)(A + off);
    }
    #pragma unroll
    for (int n = 0; n < 3; ++n) {
      const int row = wc * 48 + n * 16 + lr;
      const int off = row * 64 + (((kk * 2 + (g >> 1)) ^ ((row >> 1) & 3)) << 4) + ((g & 1) << 3);
      b[n] = *(const long long*)(B + off);
    }
    __builtin_amdgcn_s_setprio(1);
    #pragma unroll
    for (int m = 0; m < 6; ++m)
      #pragma unroll
      for (int n = 0; n < 3; ++n)
        acc[m][n] = __builtin_amdgcn_mfma_f32_16x16x32_fp8_fp8(a[m], b[n], acc[m][n], 0, 0, 0);
    __builtin_amdgcn_s_setprio(0);
  }
}

// ---- main (R13 structure): 192^2 upper-tri tiles, reg-staged counted-vmcnt pipeline
__global__ __launch_bounds__(512, 2) void gram_kernel(
    const unsigned char* __restrict__ Wb, const unsigned char* __restrict__ Gb,
    const float* __restrict__ sqbW, const float* __restrict__ sqbG,
    const float* __restrict__ scs, const double* __restrict__ ssp,
    float* __restrict__ PU, float* __restrict__ PV, double* __restrict__ PSL)
{
  __shared__ __align__(16) unsigned char lds[2][49152];  // dbuf: AW|BW|AG|BG each
  __shared__ float L[768];   // rowW|rowG|colW|colG reduction arrays
  __shared__ double pred[8], pred2[8];
  __shared__ float sS4;

  // T1: bijective XCD-chunked swizzle (nwg=253: q=31, r=5)
  const int orig = blockIdx.x;
  const int xcd = orig & 7;
  const int idx = orig >> 3;
  const int swz = (xcd < 5 ? xcd * 32 : 5 * 32 + (xcd - 5) * 31) + idx;

  // decode upper-triangular tile index: 0 <= bi <= bj < 22
  int t = swz;
  int bi = 0;
  while (t >= NT - bi) { t -= NT - bi; ++bi; }
  const int bj = bi + t;
  const bool offdiag = (bi != bj);

  const int tid = threadIdx.x;
  const int lane = tid & 63;
  const int wid = tid >> 6;
  const int wr = wid >> 2;      // 0..1  (96-row half)
  const int wc = wid & 3;       // 0..3  (48-col quarter)
  const int i0 = bi * TS;
  const int j0 = bj * TS;
  const int g = lane >> 4;
  const int lr = lane & 15;

  f32x4 accW[6][3], accG[6][3];
  #pragma unroll
  for (int m = 0; m < 6; ++m)
    #pragma unroll
    for (int n = 0; n < 3; ++n) { accW[m][n] = (f32x4)0.0f; accG[m][n] = (f32x4)0.0f; }

  // ---- K-loop: reg-staged double-buffer, ONE lgkm-only barrier per step.
  u32x4 rA[6], rB[6];
  issue_loads(Wb, Gb, bi, bj, 0, tid, rA);

  #pragma unroll
  for (int st2 = 0; st2 < 4; ++st2) {
    const int st = st2 * 2;
    write_lds(tid, rA, lds[0]);                      // auto counted-vmcnt for rA
    issue_loads(Wb, Gb, bi, bj, st + 1, tid, rB);
    __builtin_amdgcn_sched_barrier(0);
    BAR_LGKM();                                      // no vmcnt drain: rB stays in flight
    gram_pass(lds[0], lds[0] + 12288, wr, wc, lr, g, accW);
    gram_pass(lds[0] + 24576, lds[0] + 36864, wr, wc, lr, g, accG);
    write_lds(tid, rB, lds[1]);
    if (st + 2 < 8) issue_loads(Wb, Gb, bi, bj, st + 2, tid, rA);
    __builtin_amdgcn_sched_barrier(0);
    BAR_LGKM();
    gram_pass(lds[1], lds[1] + 12288, wr, wc, lr, g, accW);
    gram_pass(lds[1] + 24576, lds[1] + 36864, wr, wc, lr, g, accG);
  }
  __syncthreads();

  // ---- folded bwk: bandwidth scale computed redundantly per block ----
  {
    float cs = 0.f;
    #pragma unroll 8
    for (int p = 0; p < 32; ++p) cs += scs[p * 512 + tid];
    double p1 = (double)cs * (double)cs;
    double p2 = (tid < 256) ? ssp[tid] : 0.0;
    #pragma unroll
    for (int off = 32; off > 0; off >>= 1) {
      p1 += __shfl_xor(p1, off);
      p2 += __shfl_xor(p2, off);
    }
    if (lane == 0) { pred[wid] = p1; pred2[wid] = p2; }
    __syncthreads();
    if (tid == 0) {
      double s2 = 0.0, ss = 0.0;
      #pragma unroll
      for (int k = 0; k < 8; ++k) { s2 += pred[k]; ss += pred2[k]; }
      double sum_d2 = 2.0 * 8192.0 * ss - 2.0 * s2;
      double bw = sum_d2 / (8192.0 * 8191.0) / 4.0;
      sS4 = (float)(1.4426950408889634 / (bw * 16.0));
    }
    __syncthreads();
  }
  const float s4 = sS4;

  // zero ALL 768 reduction slots (512 threads: two passes)
  L[tid] = 0.f;
  if (tid < 256) L[512 + tid] = 0.f;

  // ---- epilogue: kernel values (f32, fexp2 — validated R11) ----
  float rjW[3], rjG[3], mjf[3];
  #pragma unroll
  for (int n = 0; n < 3; ++n) {
    const int j = j0 + wc * 48 + n * 16 + lr;
    rjW[n] = sqbW[j]; rjG[n] = sqbG[j];
    mjf[n] = (j < NROW) ? 1.f : 0.f;
  }

  float csW[3] = {0.f, 0.f, 0.f}, csG[3] = {0.f, 0.f, 0.f};
  float rsW[6][4], rsG[6][4];
  float p_loc = 0.f;

  #pragma unroll
  for (int m = 0; m < 6; ++m) {
    const int ib = i0 + wr * 96 + m * 16 + g * 4;
    float riW[4], riG[4], mif[4];
    #pragma unroll
    for (int e = 0; e < 4; ++e) {
      riW[e] = sqbW[ib + e]; riG[e] = sqbG[ib + e];
      mif[e] = (ib + e < NROW) ? 1.f : 0.f;
    }
    #pragma unroll
    for (int e = 0; e < 4; ++e) { rsW[m][e] = 0.f; rsG[m][e] = 0.f; }
    #pragma unroll
    for (int n = 0; n < 3; ++n) {
      #pragma unroll
      for (int e = 0; e < 4; ++e) {
        const float mk = mif[e] * mjf[n];
        float d2w = fmaxf(riW[e] + rjW[n] - 2.f * accW[m][n][e], 0.f);
        float yw = fexp2(-d2w * s4);
        float yw2 = yw * yw, yw4 = yw2 * yw2, yw8 = yw4 * yw4, yw16 = yw8 * yw8;
        float kw = (yw + yw2 + yw4 + yw8 + yw16) * mk;
        float d2g = fmaxf(riG[e] + rjG[n] - 2.f * accG[m][n][e], 0.f);
        float yg = fexp2(-d2g * s4);
        float yg2 = yg * yg, yg4 = yg2 * yg2, yg8 = yg4 * yg4, yg16 = yg8 * yg8;
        float kg = (yg + yg2 + yg4 + yg8 + yg16) * mk;
        p_loc = fmaf(kw, kg, p_loc);
        rsW[m][e] += kw; rsG[m][e] += kg;
        csW[n] += kw; csG[n] += kg;
      }
    }
  }

  __syncthreads();   // L zeroing visible

  // row sums -> LDS (butterfly over the 16 column-lanes, then 4-way LDS atomic)
  #pragma unroll
  for (int m = 0; m < 6; ++m)
    #pragma unroll
    for (int e = 0; e < 4; ++e) {
      float x = rsW[m][e], y = rsG[m][e];
      x += __shfl_xor(x, 1); x += __shfl_xor(x, 2); x += __shfl_xor(x, 4); x += __shfl_xor(x, 8);
      y += __shfl_xor(y, 1); y += __shfl_xor(y, 2); y += __shfl_xor(y, 4); y += __shfl_xor(y, 8);
      if (lr == 0) {
        const int rloc = wr * 96 + m * 16 + g * 4 + e;   // 0..191
        atomicAdd(&L[rloc], x);
        atomicAdd(&L[192 + rloc], y);
      }
    }

  // col sums -> LDS (butterfly over g-groups, then 2-way LDS atomic)
  if (offdiag) {
    #pragma unroll
    for (int n = 0; n < 3; ++n) {
      float x = csW[n], y = csG[n];
      x += __shfl_xor(x, 16); x += __shfl_xor(x, 32);
      y += __shfl_xor(y, 16); y += __shfl_xor(y, 32);
      if (g == 0) {
        const int cloc = wc * 48 + n * 16 + lr;          // 0..191
        atomicAdd(&L[384 + cloc], x);
        atomicAdd(&L[576 + cloc], y);
      }
    }
  }

  __syncthreads();

  // plain coalesced partial stores (no global atomics)
  if (tid < 192) {
    PU[(bi * NT + bj) * 192 + tid] = L[tid];
    PV[(bi * NT + bj) * 192 + tid] = L[192 + tid];
    if (offdiag) {
      PU[(bj * NT + bi) * 192 + tid] = L[384 + tid];
      PV[(bj * NT + bi) * 192 + tid] = L[576 + tid];
    }
  }

  // P: f32 wave butterfly -> f64 block sum -> one plain store per tile
  #pragma unroll
  for (int off = 32; off > 0; off >>= 1) p_loc += __shfl_xor(p_loc, off);
  if (lane == 0) pred[wid] = (double)p_loc;
  __syncthreads();
  if (tid == 0) {
    double ps = 0.0;
    #pragma unroll
    for (int k = 0; k < 8; ++k) ps += pred[k];
    PSL[swz] = offdiag ? 2.0 * ps : ps;
  }
}

// ---- finalize (single launch): u,v from partials; loss
__global__ __launch_bounds__(1024) void finalize(
    const float* __restrict__ PU, const float* __restrict__ PV,
    const double* __restrict__ PSL, float* __restrict__ out)
{
  __shared__ double r0[1024], r1[1024], r2[1024], r3[1024];
  const int t = threadIdx.x;
  double uv = 0.0, su = 0.0, sv = 0.0, pp = 0.0;
  for (int i = t; i < NPAD; i += 1024) {
    const int b = i / 192, ii = i - b * 192;
    double uu = 0.0, vv = 0.0;
    #pragma unroll
    for (int k = 0; k < NT; ++k) {
      uu += (double)PU[(b * NT + k) * 192 + ii];
      vv += (double)PV[(b * NT + k) * 192 + ii];
    }
    uv += uu * vv; su += uu; sv += vv;
  }
  if (t < 253) pp = PSL[t];
  r0[t] = uv; r1[t] = su; r2[t] = sv; r3[t] = pp;
  __syncthreads();
  for (int k = 512; k > 0; k >>= 1) {
    if (t < k) { r0[t] += r0[t + k]; r1[t] += r1[t + k]; r2[t] += r2[t + k]; r3[t] += r3[t + k]; }
    __syncthreads();
  }
  if (t == 0) {
    const double n = 4096.0;
    double hsic = r3[0] - (2.0 / n) * r0[0] + (r1[0] * r2[0]) / (n * n);
    out[0] = (float)(-hsic / ((n - 1.0) * (n - 1.0)));
  }
}

extern "C" void kernel_launch(void* const* d_in, const int* in_sizes, int n_in,
                              void* d_out, int out_size, void* d_ws, size_t ws_size,
                              hipStream_t stream) {
  const float* W = (const float*)d_in[0];
  const float* G = (const float*)d_in[1];
  char* ws = (char*)d_ws;
  unsigned char* Wb = (unsigned char*)(ws + WB_OFF);
  unsigned char* Gb = (unsigned char*)(ws + GB_OFF);
  float* sqbW = (float*)(ws + SQBW_OFF);
  float* sqbG = (float*)(ws + SQBG_OFF);
  float* scs = (float*)(ws + SCS_OFF);
  double* ssp = (double*)(ws + SSP_OFF);
  float* PU = (float*)(ws + PU_OFF);
  float* PV = (float*)(ws + PV_OFF);
  double* PSL = (double*)(ws + PSL_OFF);

  hipMemsetAsync(ws + ZERO_BEG, 0, ZERO_END - ZERO_BEG, stream);

  prep_rows<<<528, 256, 0, stream>>>(W, G, Wb, Gb, sqbW, sqbG, ssp, scs);
  gram_kernel<<<253, 512, 0, stream>>>(Wb, Gb, sqbW, sqbG, scs, ssp, PU, PV, PSL);
  finalize<<<1, 1024, 0, stream>>>(PU, PV, PSL, (float*)d_out);
}